// Round 2
// baseline (282.397 us; speedup 1.0000x reference)
//
#include <hip/hip_runtime.h>
#include <hip/hip_bf16.h>
#include <stdint.h>

#define Bv 128
#define Hv 256
#define INv 19
#define Pv 512
#define Cv 1024

typedef __attribute__((ext_vector_type(4))) float floatx4;
typedef __attribute__((ext_vector_type(8))) short shortx8;
typedef __attribute__((ext_vector_type(4))) unsigned int uintx4;

__device__ __forceinline__ unsigned short f2bf(float f) {
    union { float f; unsigned int u; } v; v.f = f;
    unsigned int r = v.u + 0x7fffu + ((v.u >> 16) & 1u);  // RNE
    return (unsigned short)(r >> 16);
}

__device__ __forceinline__ int swz(int r) { return ((r & 7) ^ ((r >> 3) & 7)); }

// ---------------- MLP kernels (fp32, small) ----------------

__global__ __launch_bounds__(256) void mlp_first(
    const float* __restrict__ pos, const float* __restrict__ ue,
    const float* __restrict__ bs,  const float* __restrict__ addf,
    const float* __restrict__ attW1, const float* __restrict__ attb1,
    const float* __restrict__ radW1, const float* __restrict__ radb1,
    float* __restrict__ hout)
{
    int blk = blockIdx.x;            // 0..255: net = blk>>7, b = blk&127
    int net = blk >> 7, b = blk & 127;
    const float* W = net ? radW1 : attW1;
    const float* bias = net ? radb1 : attb1;
    __shared__ float x[INv];
    int t = threadIdx.x;
    if (t < 3) x[t] = pos[b*3 + t];
    else if (t < 5) x[t] = ue[b*2 + (t-3)];
    else if (t < 9) x[t] = bs[b*4 + (t-5)];
    else if (t < 19) x[t] = addf[b*10 + (t-9)];
    __syncthreads();
    float acc = bias[t];
    #pragma unroll
    for (int k = 0; k < INv; ++k) acc += x[k] * W[k*Hv + t];
    hout[(net*Bv + b)*Hv + t] = fmaxf(acc, 0.f);
}

// hidden layer: 128 blocks x 256 threads; block = (net, 2 batch rows)
// thread: k-chunk (t>>6) of 64, o-quad (t&63); float4 W loads, 4 indep chains
__global__ __launch_bounds__(256) void mlp_layer(
    const float* __restrict__ hin,
    const float* __restrict__ attWh, const float* __restrict__ attbh,
    const float* __restrict__ radWh, const float* __restrict__ radbh,
    int layer, float* __restrict__ hout, unsigned short* __restrict__ feat)
{
    int blk = blockIdx.x;            // 128 blocks
    int net = blk >> 6, bq = blk & 63;   // rows b = bq*2, bq*2+1
    const float* W = (net ? radWh : attWh) + (size_t)layer * Hv * Hv;
    const float* bias = (net ? radbh : attbh) + layer * Hv;
    __shared__ float hr[2][Hv];
    __shared__ float part[4][2][Hv];
    int t = threadIdx.x;
    {
        int r = t >> 7, col = (t & 127) * 2;
        const float* src = hin + (size_t)(net*Bv + bq*2 + r) * Hv + col;
        float2 v = *reinterpret_cast<const float2*>(src);
        hr[r][col] = v.x; hr[r][col + 1] = v.y;
    }
    __syncthreads();
    int half = t >> 6;       // k-chunk 0..3
    int oq = t & 63;
    floatx4 a0r0 = {0.f,0.f,0.f,0.f}, a1r0 = {0.f,0.f,0.f,0.f};
    floatx4 a0r1 = {0.f,0.f,0.f,0.f}, a1r1 = {0.f,0.f,0.f,0.f};
    const float* Wp = W + (size_t)(half*64) * Hv + oq*4;
    #pragma unroll 8
    for (int kk = 0; kk < 64; kk += 2) {
        floatx4 w0 = *reinterpret_cast<const floatx4*>(Wp + (size_t)kk * Hv);
        floatx4 w1 = *reinterpret_cast<const floatx4*>(Wp + (size_t)(kk+1) * Hv);
        float h00 = hr[0][half*64 + kk], h01 = hr[0][half*64 + kk + 1];
        float h10 = hr[1][half*64 + kk], h11 = hr[1][half*64 + kk + 1];
        a0r0 += w0 * h00; a1r0 += w1 * h01;
        a0r1 += w0 * h10; a1r1 += w1 * h11;
    }
    floatx4 r0 = a0r0 + a1r0, r1 = a0r1 + a1r1;
    *reinterpret_cast<floatx4*>(&part[half][0][oq*4]) = r0;
    *reinterpret_cast<floatx4*>(&part[half][1][oq*4]) = r1;
    __syncthreads();
    {
        int r = t >> 7, o2 = (t & 127) * 2;
        #pragma unroll
        for (int j = 0; j < 2; ++j) {
            int o = o2 + j;
            float s = part[0][r][o] + part[1][r][o] + part[2][r][o] + part[3][r][o] + bias[o];
            s = fmaxf(s, 0.f);
            if (feat) feat[(size_t)(bq*2 + r) * Pv + net*Hv + o] = f2bf(s);
            else hout[(size_t)(net*Bv + bq*2 + r) * Hv + o] = s;
        }
    }
}

// ---------------- Prism helpers ----------------

// stage [64 k][256 o] fp32 chunk t (row stride 256 floats) into 8 floatx4 regs
__device__ __forceinline__ void stage_w(const float* __restrict__ Wc, int t,
                                        int kg, int oq, floatx4* r) {
    const float* s = Wc + (size_t)(t*64 + kg*8) * 256 + oq*4;
    #pragma unroll
    for (int i = 0; i < 8; ++i) r[i] = *reinterpret_cast<const floatx4*>(s + i*256);
}

// transpose 8k x 4o in regs -> 4 swizzled ds_write_b128 into WT[o][k] bf16 [256][64]
__device__ __forceinline__ void write_w(char* wb, int kg, int oq, const floatx4* r) {
    #pragma unroll
    for (int j = 0; j < 4; ++j) {
        int o = oq*4 + j;
        unsigned int p0 = (unsigned int)f2bf(r[0][j]) | ((unsigned int)f2bf(r[1][j]) << 16);
        unsigned int p1 = (unsigned int)f2bf(r[2][j]) | ((unsigned int)f2bf(r[3][j]) << 16);
        unsigned int p2 = (unsigned int)f2bf(r[4][j]) | ((unsigned int)f2bf(r[5][j]) << 16);
        unsigned int p3 = (unsigned int)f2bf(r[6][j]) | ((unsigned int)f2bf(r[7][j]) << 16);
        uintx4 v = {p0, p1, p2, p3};
        int slot = kg ^ swz(o);
        *reinterpret_cast<uintx4*>(wb + o*128 + slot*16) = v;
    }
}

// stage feat bf16 chunk t: [128 rows][64 k] -> 2 uintx4 per thread
__device__ __forceinline__ void stage_a(const unsigned short* __restrict__ feat,
                                        int t, int tid, uintx4* r) {
    #pragma unroll
    for (int q = 0; q < 2; ++q) {
        int si = tid + q*512, row = si >> 3, s = si & 7;
        r[q] = *reinterpret_cast<const uintx4*>(feat + row*Pv + t*64 + s*8);
    }
}

__device__ __forceinline__ void write_a(char* ab, int tid, const uintx4* r) {
    #pragma unroll
    for (int q = 0; q < 2; ++q) {
        int si = tid + q*512, row = si >> 3, s = si & 7;
        int slot = s ^ swz(row);
        *reinterpret_cast<uintx4*>(ab + row*128 + slot*16) = r[q];
    }
}

__device__ __forceinline__ void mfma_chunk_l1(const char* ab, const char* wb,
                                              int wm, int wn, int l,
                                              floatx4 (&acc)[4][4]) {
    #pragma unroll
    for (int ks = 0; ks < 2; ++ks) {
        shortx8 af[4], bf[4];
        #pragma unroll
        for (int m = 0; m < 4; ++m) {
            int row = wm*64 + m*16 + (l & 15);
            int slot = (ks*4 + (l >> 4)) ^ swz(row);
            af[m] = *reinterpret_cast<const shortx8*>(ab + row*128 + slot*16);
        }
        #pragma unroll
        for (int n = 0; n < 4; ++n) {
            int o = wn*64 + n*16 + (l & 15);
            int slot = (ks*4 + (l >> 4)) ^ swz(o);
            bf[n] = *reinterpret_cast<const shortx8*>(wb + o*128 + slot*16);
        }
        #pragma unroll
        for (int m = 0; m < 4; ++m)
            #pragma unroll
            for (int n = 0; n < 4; ++n)
                acc[m][n] = __builtin_amdgcn_mfma_f32_16x16x32_bf16(af[m], bf[n], acc[m][n], 0, 0, 0);
    }
}

__device__ __forceinline__ void mfma_chunk_l2(const char* h1, const char* wb, int t2,
                                              int wm, int wn, int l,
                                              floatx4 (&acc)[4][4]) {
    #pragma unroll
    for (int ks = 0; ks < 2; ++ks) {
        shortx8 af[4], bf[4];
        #pragma unroll
        for (int m = 0; m < 4; ++m) {
            int row = wm*64 + m*16 + (l & 15);
            int k2 = t2*64 + ks*32 + (l >> 4)*8;
            af[m] = *reinterpret_cast<const shortx8*>(h1 + row*512 + ((k2*2) ^ (swz(row) << 4)));
        }
        #pragma unroll
        for (int n = 0; n < 4; ++n) {
            int o = wn*64 + n*16 + (l & 15);
            int slot = (ks*4 + (l >> 4)) ^ swz(o);
            bf[n] = *reinterpret_cast<const shortx8*>(wb + o*128 + slot*16);
        }
        #pragma unroll
        for (int m = 0; m < 4; ++m)
            #pragma unroll
            for (int n = 0; n < 4; ++n)
                acc[m][n] = __builtin_amdgcn_mfma_f32_16x16x32_bf16(af[m], bf[n], acc[m][n], 0, 0, 0);
    }
}

// ---------------- Prism kernel: one block per subcarrier ----------------

__global__ __launch_bounds__(512) void prism_kernel(
    const unsigned short* __restrict__ feat,
    const float* __restrict__ W1, const float* __restrict__ b1,
    const float* __restrict__ W2, const float* __restrict__ b2,
    const float* __restrict__ W3, const float* __restrict__ b3,
    float* __restrict__ out)
{
    __shared__ __align__(16) char smem[131072];
    const int c = blockIdx.x;
    const int tid = threadIdx.x;
    const int l = tid & 63;
    const int w = tid >> 6;
    const int wm = w >> 2;      // 0..1
    const int wn = w & 3;       // 0..3
    const int kg = w;           // k-group for staging
    const int oq = l;           // o-quad for staging

    const float* W1c = W1 + (size_t)c * (Pv * Hv);
    const float* W2c = W2 + (size_t)c * (Hv * Hv);

    char* ab0 = smem;
    char* ab1 = smem + 16384;
    char* wb0 = smem + 32768;
    char* wb1 = smem + 65536;
    char* h1  = smem;                 // [128][512B] bf16, after layer 1
    char* w2b0 = smem + 65536;
    char* w2b1 = smem + 98304;
    float* subws = (float*)smem;      // [4][128] at the very end

    float bias1v[4], bias2v[4], w3v[4];
    #pragma unroll
    for (int n = 0; n < 4; ++n) {
        int o = wn*64 + n*16 + (l & 15);
        bias1v[n] = b1[c*Hv + o];
        bias2v[n] = b2[c*Hv + o];
        w3v[n]    = W3[c*Hv + o];
    }
    float b3v = b3[c];

    floatx4 wr0[8], wr1[8];
    uintx4 ar0[2], ar1[2];

    // ---- Layer 1: [128,512]x[512,256], 8 K-chunks of 64 ----
    stage_w(W1c, 0, kg, oq, wr0);
    stage_a(feat, 0, tid, ar0);
    write_w(wb0, kg, oq, wr0);
    write_a(ab0, tid, ar0);
    __syncthreads();
    stage_w(W1c, 1, kg, oq, wr1);
    stage_a(feat, 1, tid, ar1);

    floatx4 acc[4][4];
    #pragma unroll
    for (int m = 0; m < 4; ++m)
        #pragma unroll
        for (int n = 0; n < 4; ++n)
            acc[m][n] = (floatx4){0.f, 0.f, 0.f, 0.f};

    #pragma unroll
    for (int t = 0; t < 8; ++t) {
        if (t + 2 < 8) {   // issue next-next chunk loads first (stay in flight)
            if ((t & 1) == 0) { stage_w(W1c, t+2, kg, oq, wr0); stage_a(feat, t+2, tid, ar0); }
            else              { stage_w(W1c, t+2, kg, oq, wr1); stage_a(feat, t+2, tid, ar1); }
        }
        const char* ab = (t & 1) ? ab1 : ab0;
        const char* wb = (t & 1) ? wb1 : wb0;
        mfma_chunk_l1(ab, wb, wm, wn, l, acc);
        if (t + 1 < 8) {
            char* abn = ((t+1) & 1) ? ab1 : ab0;
            char* wbn = ((t+1) & 1) ? wb1 : wb0;
            if ((t+1) & 1) { write_w(wbn, kg, oq, wr1); write_a(abn, tid, ar1); }
            else           { write_w(wbn, kg, oq, wr0); write_a(abn, tid, ar0); }
        }
        __syncthreads();
    }

    // ---- epilogue 1: h1 = relu(acc + b1) -> LDS bf16 [128][256] (swizzled) ----
    #pragma unroll
    for (int m = 0; m < 4; ++m) {
        #pragma unroll
        for (int n = 0; n < 4; ++n) {
            int o = wn*64 + n*16 + (l & 15);
            #pragma unroll
            for (int jj = 0; jj < 4; ++jj) {
                int bb = wm*64 + m*16 + (l >> 4)*4 + jj;
                float v = fmaxf(acc[m][n][jj] + bias1v[n], 0.f);
                *(unsigned short*)(h1 + bb*512 + ((o*2) ^ (swz(bb) << 4))) = f2bf(v);
            }
        }
    }
    __syncthreads();

    // ---- Layer 2: [128,256]x[256,256], 4 K-chunks of 64 ----
    stage_w(W2c, 0, kg, oq, wr0);
    write_w(w2b0, kg, oq, wr0);
    __syncthreads();
    stage_w(W2c, 1, kg, oq, wr1);

    floatx4 acc2[4][4];
    #pragma unroll
    for (int m = 0; m < 4; ++m)
        #pragma unroll
        for (int n = 0; n < 4; ++n)
            acc2[m][n] = (floatx4){0.f, 0.f, 0.f, 0.f};

    #pragma unroll
    for (int t = 0; t < 4; ++t) {
        if (t + 2 < 4) {
            if ((t & 1) == 0) stage_w(W2c, t+2, kg, oq, wr0);
            else              stage_w(W2c, t+2, kg, oq, wr1);
        }
        const char* wb = (t & 1) ? w2b1 : w2b0;
        mfma_chunk_l2(h1, wb, t, wm, wn, l, acc2);
        if (t + 1 < 4) {
            char* wbn = ((t+1) & 1) ? w2b1 : w2b0;
            if ((t+1) & 1) write_w(wbn, kg, oq, wr1);
            else           write_w(wbn, kg, oq, wr0);
        }
        __syncthreads();
    }

    // ---- Layer 3: sub[b] = relu(h2)·W3 + b3 ----
    float p[4][4];
    #pragma unroll
    for (int m = 0; m < 4; ++m)
        #pragma unroll
        for (int jj = 0; jj < 4; ++jj) {
            float s = 0.f;
            #pragma unroll
            for (int n = 0; n < 4; ++n)
                s += fmaxf(acc2[m][n][jj] + bias2v[n], 0.f) * w3v[n];
            p[m][jj] = s;
        }
    #pragma unroll
    for (int m = 0; m < 4; ++m)
        #pragma unroll
        for (int jj = 0; jj < 4; ++jj) {
            p[m][jj] += __shfl_xor(p[m][jj], 1, 64);
            p[m][jj] += __shfl_xor(p[m][jj], 2, 64);
            p[m][jj] += __shfl_xor(p[m][jj], 4, 64);
            p[m][jj] += __shfl_xor(p[m][jj], 8, 64);
        }
    __syncthreads();   // all reads of h1 / w2 bufs done
    {
        int t16 = l & 15;
        // static-index select of p[t16>>2][t16&3] (avoid scratch)
        float pv = 0.f;
        #pragma unroll
        for (int m = 0; m < 4; ++m)
            #pragma unroll
            for (int jj = 0; jj < 4; ++jj)
                if (m == (t16 >> 2) && jj == (t16 & 3)) pv = p[m][jj];
        int bb = wm*64 + (t16 >> 2)*16 + (l >> 4)*4 + (t16 & 3);
        subws[wn*128 + bb] = pv;
    }
    __syncthreads();
    if (tid < 128) {
        float s = subws[tid] + subws[128 + tid] + subws[256 + tid] + subws[384 + tid] + b3v;
        out[(size_t)tid * Cv + c] = s;
    }
}

// ---------------- mimo epilogue ----------------

__global__ __launch_bounds__(256) void mimo_kernel(
    const float* __restrict__ sub, const float* __restrict__ mW,
    const float* __restrict__ mB, float* __restrict__ out)
{
    int b = blockIdx.x;
    int t = threadIdx.x;
    float s = 0.f;
    #pragma unroll
    for (int j = 0; j < 4; ++j) s += sub[b*Cv + t + j*256];
    #pragma unroll
    for (int m = 1; m < 64; m <<= 1) s += __shfl_xor(s, m, 64);
    __shared__ float red[4];
    if ((t & 63) == 0) red[t >> 6] = s;
    __syncthreads();
    if (t < 8) {
        float mean = (red[0] + red[1] + red[2] + red[3]) * (1.0f / 1024.0f);
        out[Bv * Cv + b*8 + t] = mean * mW[t] + mB[t];
    }
}

// ---------------- launch ----------------

extern "C" void kernel_launch(void* const* d_in, const int* in_sizes, int n_in,
                              void* d_out, int out_size, void* d_ws, size_t ws_size,
                              hipStream_t stream) {
    (void)in_sizes; (void)n_in; (void)out_size; (void)ws_size;
    const float* pos   = (const float*)d_in[0];
    const float* ue    = (const float*)d_in[1];
    const float* bsant = (const float*)d_in[2];
    const float* addf  = (const float*)d_in[3];
    const float* attW1 = (const float*)d_in[4];
    const float* attb1 = (const float*)d_in[5];
    const float* attWh = (const float*)d_in[6];
    const float* attbh = (const float*)d_in[7];
    const float* radW1 = (const float*)d_in[8];
    const float* radb1 = (const float*)d_in[9];
    const float* radWh = (const float*)d_in[10];
    const float* radbh = (const float*)d_in[11];
    const float* pW1   = (const float*)d_in[12];
    const float* pb1   = (const float*)d_in[13];
    const float* pW2   = (const float*)d_in[14];
    const float* pb2   = (const float*)d_in[15];
    const float* pW3   = (const float*)d_in[16];
    const float* pb3   = (const float*)d_in[17];
    const float* mW    = (const float*)d_in[18];
    const float* mB    = (const float*)d_in[19];
    float* out = (float*)d_out;

    float* h0 = (float*)d_ws;                       // [2][128][256] fp32
    float* hA = h0 + 2*Bv*Hv;                       // [2][128][256] fp32
    unsigned short* feat = (unsigned short*)(h0 + 4*Bv*Hv);  // [128][512] bf16

    mlp_first<<<256, 256, 0, stream>>>(pos, ue, bsant, addf, attW1, attb1, radW1, radb1, h0);
    float* hin = h0; float* hout = hA;
    for (int i = 0; i < 6; ++i) {
        mlp_layer<<<128, 256, 0, stream>>>(hin, attWh, attbh, radWh, radbh, i, hout, nullptr);
        float* tmp = hin; hin = hout; hout = tmp;
    }
    mlp_layer<<<128, 256, 0, stream>>>(hin, attWh, attbh, radWh, radbh, 6, nullptr, feat);
    prism_kernel<<<Cv, 512, 0, stream>>>(feat, pW1, pb1, pW2, pb2, pW3, pb3, out);
    mimo_kernel<<<Bv, 256, 0, stream>>>(out, mW, mB, out);
}

// Round 3
// 202.797 us; speedup vs baseline: 1.3925x; 1.3925x over previous
//
#include <hip/hip_runtime.h>
#include <hip/hip_bf16.h>
#include <stdint.h>

#define Bv 128
#define Hv 256
#define INv 19
#define Pv 512
#define Cv 1024
#define NLh 7

typedef __attribute__((ext_vector_type(4))) float floatx4;
typedef __attribute__((ext_vector_type(8))) short shortx8;
typedef __attribute__((ext_vector_type(4))) unsigned int uintx4;

__device__ __forceinline__ unsigned short f2bf(float f) {
    union { float f; unsigned int u; } v; v.f = f;
    unsigned int r = v.u + 0x7fffu + ((v.u >> 16) & 1u);  // RNE
    return (unsigned short)(r >> 16);
}

__device__ __forceinline__ int swz(int r) { return ((r & 7) ^ ((r >> 3) & 7)); }

// LDS-only barrier: waits own DS ops, leaves global prefetch loads in flight
// (vmcnt stays counted by the compiler's dependency waits). [T4 mechanism]
#define BAR() do { asm volatile("s_waitcnt lgkmcnt(0)" ::: "memory"); \
                   __builtin_amdgcn_s_barrier(); } while (0)

// ---------------- fused MLP: first + 7 hidden layers, one launch ----------------
// 128 blocks x 256 threads; block = (net, 2 batch rows). Rows independent
// across layers -> only block-local barriers between layers.
__global__ __launch_bounds__(256) void mlp_fused(
    const float* __restrict__ pos, const float* __restrict__ ue,
    const float* __restrict__ bs,  const float* __restrict__ addf,
    const float* __restrict__ attW1, const float* __restrict__ attb1,
    const float* __restrict__ attWh, const float* __restrict__ attbh,
    const float* __restrict__ radW1, const float* __restrict__ radb1,
    const float* __restrict__ radWh, const float* __restrict__ radbh,
    unsigned short* __restrict__ feat)   // bf16 [128][512]
{
    int blk = blockIdx.x;              // 128 blocks
    int net = blk >> 6, bq = blk & 63; // rows 2bq, 2bq+1
    const float* W1 = net ? radW1 : attW1;
    const float* b1 = net ? radb1 : attb1;
    const float* Wh = net ? radWh : attWh;
    const float* bh = net ? radbh : attbh;
    __shared__ float xs[2][INv];
    __shared__ float hr[2][Hv];
    __shared__ float part[4][2][Hv];
    int t = threadIdx.x;
    if (t < 2 * INv) {
        int r = t / INv, k = t - r * INv;
        int b = bq * 2 + r;
        float v;
        if (k < 3) v = pos[b*3 + k];
        else if (k < 5) v = ue[b*2 + (k-3)];
        else if (k < 9) v = bs[b*4 + (k-5)];
        else v = addf[b*10 + (k-9)];
        xs[r][k] = v;
    }
    __syncthreads();
    {   // first layer: thread t -> output o=t, both rows
        float a0 = b1[t], a1 = a0;
        #pragma unroll
        for (int k = 0; k < INv; ++k) {
            float w = W1[k*Hv + t];
            a0 += xs[0][k] * w;
            a1 += xs[1][k] * w;
        }
        hr[0][t] = fmaxf(a0, 0.f);
        hr[1][t] = fmaxf(a1, 0.f);
    }
    __syncthreads();
    int half = t >> 6, oq = t & 63;
    for (int layer = 0; layer < NLh; ++layer) {
        const float* W = Wh + (size_t)layer * Hv * Hv;
        const float* Wp = W + (size_t)(half * 64) * Hv + oq * 4;
        floatx4 a0r0 = {0.f,0.f,0.f,0.f}, a1r0 = {0.f,0.f,0.f,0.f};
        floatx4 a0r1 = {0.f,0.f,0.f,0.f}, a1r1 = {0.f,0.f,0.f,0.f};
        #pragma unroll 8
        for (int kk = 0; kk < 64; kk += 2) {
            floatx4 w0 = *reinterpret_cast<const floatx4*>(Wp + (size_t)kk * Hv);
            floatx4 w1 = *reinterpret_cast<const floatx4*>(Wp + (size_t)(kk+1) * Hv);
            float h00 = hr[0][half*64 + kk], h01 = hr[0][half*64 + kk + 1];
            float h10 = hr[1][half*64 + kk], h11 = hr[1][half*64 + kk + 1];
            a0r0 += w0 * h00; a1r0 += w1 * h01;
            a0r1 += w0 * h10; a1r1 += w1 * h11;
        }
        floatx4 r0 = a0r0 + a1r0, r1 = a0r1 + a1r1;
        *reinterpret_cast<floatx4*>(&part[half][0][oq*4]) = r0;
        *reinterpret_cast<floatx4*>(&part[half][1][oq*4]) = r1;
        __syncthreads();
        int r = t >> 7, o2 = (t & 127) * 2;
        const float* bias = bh + layer * Hv;
        float s0 = part[0][r][o2]   + part[1][r][o2]   + part[2][r][o2]   + part[3][r][o2]   + bias[o2];
        float s1 = part[0][r][o2+1] + part[1][r][o2+1] + part[2][r][o2+1] + part[3][r][o2+1] + bias[o2+1];
        s0 = fmaxf(s0, 0.f); s1 = fmaxf(s1, 0.f);
        if (layer == NLh - 1) {
            feat[(size_t)(bq*2 + r) * Pv + net*Hv + o2]     = f2bf(s0);
            feat[(size_t)(bq*2 + r) * Pv + net*Hv + o2 + 1] = f2bf(s1);
        } else {
            hr[r][o2] = s0; hr[r][o2+1] = s1;
        }
        __syncthreads();
    }
}

// ---------------- Prism helpers ----------------

// stage [64 k][256 o] fp32 chunk t (row stride 256 floats) into 8 floatx4 regs
__device__ __forceinline__ void stage_w(const float* __restrict__ Wc, int t,
                                        int kg, int oq, floatx4* r) {
    const float* s = Wc + (size_t)(t*64 + kg*8) * 256 + oq*4;
    #pragma unroll
    for (int i = 0; i < 8; ++i) r[i] = *reinterpret_cast<const floatx4*>(s + i*256);
}

// transpose 8k x 4o in regs -> 4 swizzled ds_write_b128 into WT[o][k] bf16 [256][64]
__device__ __forceinline__ void write_w(char* wb, int kg, int oq, const floatx4* r) {
    #pragma unroll
    for (int j = 0; j < 4; ++j) {
        int o = oq*4 + j;
        unsigned int p0 = (unsigned int)f2bf(r[0][j]) | ((unsigned int)f2bf(r[1][j]) << 16);
        unsigned int p1 = (unsigned int)f2bf(r[2][j]) | ((unsigned int)f2bf(r[3][j]) << 16);
        unsigned int p2 = (unsigned int)f2bf(r[4][j]) | ((unsigned int)f2bf(r[5][j]) << 16);
        unsigned int p3 = (unsigned int)f2bf(r[6][j]) | ((unsigned int)f2bf(r[7][j]) << 16);
        uintx4 v = {p0, p1, p2, p3};
        int slot = kg ^ swz(o);
        *reinterpret_cast<uintx4*>(wb + o*128 + slot*16) = v;
    }
}

// stage feat bf16 chunk t: [128 rows][64 k] -> 2 uintx4 per thread
__device__ __forceinline__ void stage_a(const unsigned short* __restrict__ feat,
                                        int t, int tid, uintx4* r) {
    #pragma unroll
    for (int q = 0; q < 2; ++q) {
        int si = tid + q*512, row = si >> 3, s = si & 7;
        r[q] = *reinterpret_cast<const uintx4*>(feat + row*Pv + t*64 + s*8);
    }
}

__device__ __forceinline__ void write_a(char* ab, int tid, const uintx4* r) {
    #pragma unroll
    for (int q = 0; q < 2; ++q) {
        int si = tid + q*512, row = si >> 3, s = si & 7;
        int slot = s ^ swz(row);
        *reinterpret_cast<uintx4*>(ab + row*128 + slot*16) = r[q];
    }
}

__device__ __forceinline__ void mfma_chunk_l1(const char* ab, const char* wb,
                                              int wm, int wn, int l,
                                              floatx4 (&acc)[4][4]) {
    #pragma unroll
    for (int ks = 0; ks < 2; ++ks) {
        shortx8 af[4], bf[4];
        #pragma unroll
        for (int m = 0; m < 4; ++m) {
            int row = wm*64 + m*16 + (l & 15);
            int slot = (ks*4 + (l >> 4)) ^ swz(row);
            af[m] = *reinterpret_cast<const shortx8*>(ab + row*128 + slot*16);
        }
        #pragma unroll
        for (int n = 0; n < 4; ++n) {
            int o = wn*64 + n*16 + (l & 15);
            int slot = (ks*4 + (l >> 4)) ^ swz(o);
            bf[n] = *reinterpret_cast<const shortx8*>(wb + o*128 + slot*16);
        }
        #pragma unroll
        for (int m = 0; m < 4; ++m)
            #pragma unroll
            for (int n = 0; n < 4; ++n)
                acc[m][n] = __builtin_amdgcn_mfma_f32_16x16x32_bf16(af[m], bf[n], acc[m][n], 0, 0, 0);
    }
}

__device__ __forceinline__ void mfma_chunk_l2(const char* h1, const char* wb, int t2,
                                              int wm, int wn, int l,
                                              floatx4 (&acc)[4][4]) {
    #pragma unroll
    for (int ks = 0; ks < 2; ++ks) {
        shortx8 af[4], bf[4];
        #pragma unroll
        for (int m = 0; m < 4; ++m) {
            int row = wm*64 + m*16 + (l & 15);
            int k2 = t2*64 + ks*32 + (l >> 4)*8;
            af[m] = *reinterpret_cast<const shortx8*>(h1 + row*512 + ((k2*2) ^ (swz(row) << 4)));
        }
        #pragma unroll
        for (int n = 0; n < 4; ++n) {
            int o = wn*64 + n*16 + (l & 15);
            int slot = (ks*4 + (l >> 4)) ^ swz(o);
            bf[n] = *reinterpret_cast<const shortx8*>(wb + o*128 + slot*16);
        }
        #pragma unroll
        for (int m = 0; m < 4; ++m)
            #pragma unroll
            for (int n = 0; n < 4; ++n)
                acc[m][n] = __builtin_amdgcn_mfma_f32_16x16x32_bf16(af[m], bf[n], acc[m][n], 0, 0, 0);
    }
}

// ---------------- Prism kernel: one block per subcarrier ----------------

__global__ __launch_bounds__(512) void prism_kernel(
    const unsigned short* __restrict__ feat,
    const float* __restrict__ W1, const float* __restrict__ b1,
    const float* __restrict__ W2, const float* __restrict__ b2,
    const float* __restrict__ W3, const float* __restrict__ b3,
    float* __restrict__ out)
{
    __shared__ __align__(16) char smem[131072];
    const int c = blockIdx.x;
    const int tid = threadIdx.x;
    const int l = tid & 63;
    const int w = tid >> 6;
    const int wm = w >> 2;      // 0..1
    const int wn = w & 3;       // 0..3
    const int kg = w;           // k-group for staging
    const int oq = l;           // o-quad for staging

    const float* W1c = W1 + (size_t)c * (Pv * Hv);
    const float* W2c = W2 + (size_t)c * (Hv * Hv);

    char* ab0 = smem;
    char* ab1 = smem + 16384;
    char* wb0 = smem + 32768;
    char* wb1 = smem + 65536;
    char* h1  = smem;                 // [128][512B] bf16, after layer 1
    char* w2b0 = smem + 65536;
    char* w2b1 = smem + 98304;
    float* subws = (float*)smem;      // [4][128] at the very end

    float bias1v[4], bias2v[4], w3v[4];
    #pragma unroll
    for (int n = 0; n < 4; ++n) {
        int o = wn*64 + n*16 + (l & 15);
        bias1v[n] = b1[c*Hv + o];
        bias2v[n] = b2[c*Hv + o];
        w3v[n]    = W3[c*Hv + o];
    }
    float b3v = b3[c];

    floatx4 wr0[8], wr1[8];
    uintx4 ar0[2], ar1[2];

    // ---- Layer 1 prologue: issue chunk0 AND chunk1 loads before first write ----
    stage_w(W1c, 0, kg, oq, wr0);
    stage_a(feat, 0, tid, ar0);
    stage_w(W1c, 1, kg, oq, wr1);
    stage_a(feat, 1, tid, ar1);
    write_w(wb0, kg, oq, wr0);
    write_a(ab0, tid, ar0);
    BAR();

    floatx4 acc[4][4];
    #pragma unroll
    for (int m = 0; m < 4; ++m)
        #pragma unroll
        for (int n = 0; n < 4; ++n)
            acc[m][n] = (floatx4){0.f, 0.f, 0.f, 0.f};

    #pragma unroll
    for (int t = 0; t < 8; ++t) {
        if (t + 2 < 8) {   // issue next-next chunk loads first (stay in flight)
            if ((t & 1) == 0) { stage_w(W1c, t+2, kg, oq, wr0); stage_a(feat, t+2, tid, ar0); }
            else              { stage_w(W1c, t+2, kg, oq, wr1); stage_a(feat, t+2, tid, ar1); }
        } else if (t == 6) { // bridge L1->L2: prefetch W2 chunk 0/1 in the idle slots
            stage_w(W2c, 0, kg, oq, wr0);
        } else {             // t == 7
            stage_w(W2c, 1, kg, oq, wr1);
        }
        const char* ab = (t & 1) ? ab1 : ab0;
        const char* wb = (t & 1) ? wb1 : wb0;
        mfma_chunk_l1(ab, wb, wm, wn, l, acc);
        if (t + 1 < 8) {
            char* abn = ((t+1) & 1) ? ab1 : ab0;
            char* wbn = ((t+1) & 1) ? wb1 : wb0;
            if ((t+1) & 1) { write_w(wbn, kg, oq, wr1); write_a(abn, tid, ar1); }
            else           { write_w(wbn, kg, oq, wr0); write_a(abn, tid, ar0); }
        }
        BAR();
    }

    // ---- epilogue 1: h1 = relu(acc + b1) -> LDS bf16 [128][256] (swizzled) ----
    #pragma unroll
    for (int m = 0; m < 4; ++m) {
        #pragma unroll
        for (int n = 0; n < 4; ++n) {
            int o = wn*64 + n*16 + (l & 15);
            #pragma unroll
            for (int jj = 0; jj < 4; ++jj) {
                int bb = wm*64 + m*16 + (l >> 4)*4 + jj;
                float v = fmaxf(acc[m][n][jj] + bias1v[n], 0.f);
                *(unsigned short*)(h1 + bb*512 + ((o*2) ^ (swz(bb) << 4))) = f2bf(v);
            }
        }
    }
    // W2 chunk 0 (prefetched at t=6) into its buffer; chunk 1 stays in wr1
    write_w(w2b0, kg, oq, wr0);
    BAR();

    floatx4 acc2[4][4];
    #pragma unroll
    for (int m = 0; m < 4; ++m)
        #pragma unroll
        for (int n = 0; n < 4; ++n)
            acc2[m][n] = (floatx4){0.f, 0.f, 0.f, 0.f};

    // ---- Layer 2: [128,256]x[256,256], 4 K-chunks of 64 ----
    #pragma unroll
    for (int t = 0; t < 4; ++t) {
        if (t + 2 < 4) {
            if ((t & 1) == 0) stage_w(W2c, t+2, kg, oq, wr0);
            else              stage_w(W2c, t+2, kg, oq, wr1);
        }
        const char* wb = (t & 1) ? w2b1 : w2b0;
        mfma_chunk_l2(h1, wb, t, wm, wn, l, acc2);
        if (t + 1 < 4) {
            char* wbn = ((t+1) & 1) ? w2b1 : w2b0;
            if ((t+1) & 1) write_w(wbn, kg, oq, wr1);
            else           write_w(wbn, kg, oq, wr0);
        }
        BAR();
    }

    // ---- Layer 3: sub[b] = relu(h2)·W3 + b3 ----
    float p[4][4];
    #pragma unroll
    for (int m = 0; m < 4; ++m)
        #pragma unroll
        for (int jj = 0; jj < 4; ++jj) {
            float s = 0.f;
            #pragma unroll
            for (int n = 0; n < 4; ++n)
                s += fmaxf(acc2[m][n][jj] + bias2v[n], 0.f) * w3v[n];
            p[m][jj] = s;
        }
    #pragma unroll
    for (int m = 0; m < 4; ++m)
        #pragma unroll
        for (int jj = 0; jj < 4; ++jj) {
            p[m][jj] += __shfl_xor(p[m][jj], 1, 64);
            p[m][jj] += __shfl_xor(p[m][jj], 2, 64);
            p[m][jj] += __shfl_xor(p[m][jj], 4, 64);
            p[m][jj] += __shfl_xor(p[m][jj], 8, 64);
        }
    BAR();   // all reads of h1 / w2 bufs done before subws overwrite
    {
        int t16 = l & 15;
        float pv = 0.f;
        #pragma unroll
        for (int m = 0; m < 4; ++m)
            #pragma unroll
            for (int jj = 0; jj < 4; ++jj)
                if (m == (t16 >> 2) && jj == (t16 & 3)) pv = p[m][jj];
        int bb = wm*64 + (t16 >> 2)*16 + (l >> 4)*4 + (t16 & 3);
        subws[wn*128 + bb] = pv;
    }
    BAR();
    if (tid < 128) {
        float s = subws[tid] + subws[128 + tid] + subws[256 + tid] + subws[384 + tid] + b3v;
        out[(size_t)tid * Cv + c] = s;
    }
}

// ---------------- mimo epilogue ----------------

__global__ __launch_bounds__(256) void mimo_kernel(
    const float* __restrict__ sub, const float* __restrict__ mW,
    const float* __restrict__ mB, float* __restrict__ out)
{
    int b = blockIdx.x;
    int t = threadIdx.x;
    float s = 0.f;
    #pragma unroll
    for (int j = 0; j < 4; ++j) s += sub[b*Cv + t + j*256];
    #pragma unroll
    for (int m = 1; m < 64; m <<= 1) s += __shfl_xor(s, m, 64);
    __shared__ float red[4];
    if ((t & 63) == 0) red[t >> 6] = s;
    __syncthreads();
    if (t < 8) {
        float mean = (red[0] + red[1] + red[2] + red[3]) * (1.0f / 1024.0f);
        out[Bv * Cv + b*8 + t] = mean * mW[t] + mB[t];
    }
}

// ---------------- launch ----------------

extern "C" void kernel_launch(void* const* d_in, const int* in_sizes, int n_in,
                              void* d_out, int out_size, void* d_ws, size_t ws_size,
                              hipStream_t stream) {
    (void)in_sizes; (void)n_in; (void)out_size; (void)ws_size;
    const float* pos   = (const float*)d_in[0];
    const float* ue    = (const float*)d_in[1];
    const float* bsant = (const float*)d_in[2];
    const float* addf  = (const float*)d_in[3];
    const float* attW1 = (const float*)d_in[4];
    const float* attb1 = (const float*)d_in[5];
    const float* attWh = (const float*)d_in[6];
    const float* attbh = (const float*)d_in[7];
    const float* radW1 = (const float*)d_in[8];
    const float* radb1 = (const float*)d_in[9];
    const float* radWh = (const float*)d_in[10];
    const float* radbh = (const float*)d_in[11];
    const float* pW1   = (const float*)d_in[12];
    const float* pb1   = (const float*)d_in[13];
    const float* pW2   = (const float*)d_in[14];
    const float* pb2   = (const float*)d_in[15];
    const float* pW3   = (const float*)d_in[16];
    const float* pb3   = (const float*)d_in[17];
    const float* mW    = (const float*)d_in[18];
    const float* mB    = (const float*)d_in[19];
    float* out = (float*)d_out;

    unsigned short* feat = (unsigned short*)d_ws;   // [128][512] bf16

    mlp_fused<<<128, 256, 0, stream>>>(pos, ue, bsant, addf,
                                       attW1, attb1, attWh, attbh,
                                       radW1, radb1, radWh, radbh, feat);
    prism_kernel<<<Cv, 512, 0, stream>>>(feat, pW1, pb1, pW2, pb2, pW3, pb3, out);
    mimo_kernel<<<Bv, 256, 0, stream>>>(out, mW, mB, out);
}